// Round 10
// baseline (189.565 us; speedup 1.0000x reference)
//
#include <hip/hip_runtime.h>
#include <hip/hip_bf16.h>
#include <math.h>

#define DIM    384
#define NHEAD  8
#define HDIM   48
#define NTOK   2048              // tokens per batch (8*16*16)
#define BATCH  2
#define TOKS   (BATCH * NTOK)    // 4096
#define HIDDEN 1536

typedef __bf16 bf16x8 __attribute__((ext_vector_type(8)));
typedef float  f32x4  __attribute__((ext_vector_type(4)));
typedef unsigned short u16;

union bfu { __hip_bfloat16 h; u16 u; };

__device__ __forceinline__ void load_lds16(const void* g, void* l) {
    __builtin_amdgcn_global_load_lds(
        (const __attribute__((address_space(1))) void*)g,
        (__attribute__((address_space(3))) void*)l, 16, 0, 0);
}

// ---------------------------------------------------------------------------
// prep: 4 weight cast+transposes (blocks 0..1727) + fused input transpose/LN1
// (blocks 1728..1855) in ONE dispatch.
// ---------------------------------------------------------------------------
__global__ __launch_bounds__(256) void prep(
    const float* __restrict__ Wqkv, const float* __restrict__ Wo,
    const float* __restrict__ W1,   const float* __restrict__ W2,
    __hip_bfloat16* __restrict__ WqkvT, __hip_bfloat16* __restrict__ WoT,
    __hip_bfloat16* __restrict__ W1T,   __hip_bfloat16* __restrict__ W2T,
    const float* __restrict__ x, const float* __restrict__ g,
    const float* __restrict__ bta,
    float* __restrict__ hOut, __hip_bfloat16* __restrict__ y) {
    __shared__ __align__(16) char smem[384 * 33 * 4];
    int id = blockIdx.x;
    int tid = threadIdx.x;
    if (id < 1728) {
        float (*t)[33] = (float(*)[33])smem;
        const float* src; __hip_bfloat16* dst; int R, C;
        if (id < 432)       { src = Wqkv; dst = WqkvT; R = 384;  C = 1152; }
        else if (id < 576)  { id -= 432;  src = Wo;    dst = WoT;  R = 384;  C = 384; }
        else if (id < 1152) { id -= 576;  src = W1;    dst = W1T;  R = 384;  C = 1536; }
        else                { id -= 1152; src = W2;    dst = W2T;  R = 1536; C = 384; }
        int tc = C / 32;
        int i0 = (id / tc) * 32, j0 = (id % tc) * 32;
        int tx = tid & 31, ty = tid >> 5;
#pragma unroll
        for (int k = 0; k < 32; k += 8)
            t[ty + k][tx] = src[(size_t)(i0 + ty + k) * C + j0 + tx];
        __syncthreads();
#pragma unroll
        for (int k = 0; k < 32; k += 8)
            dst[(size_t)(j0 + ty + k) * R + i0 + tx] = __float2bfloat16(t[tx][ty + k]);
    } else {
        float* t = (float*)smem;
        int id2 = id - 1728;
        int n0 = (id2 & 63) * 32, b = id2 >> 6;
        const float* xb = x + (size_t)b * DIM * NTOK;
        for (int idx = tid; idx < 384 * 32; idx += 256) {
            int c = idx >> 5, n = idx & 31;
            t[c * 33 + n] = xb[(size_t)c * NTOK + n0 + n];
        }
        __syncthreads();
        int wid = tid >> 6, lane = tid & 63;
#pragma unroll
        for (int it = 0; it < 8; ++it) {
            int tl = it * 4 + wid;
            float v[6];
            float s = 0.f;
#pragma unroll
            for (int i = 0; i < 6; ++i) { v[i] = t[(lane + 64 * i) * 33 + tl]; s += v[i]; }
#pragma unroll
            for (int o = 32; o; o >>= 1) s += __shfl_xor(s, o, 64);
            float mu = s * (1.f / DIM);
            float s2 = 0.f;
#pragma unroll
            for (int i = 0; i < 6; ++i) { float d = v[i] - mu; s2 += d * d; }
#pragma unroll
            for (int o = 32; o; o >>= 1) s2 += __shfl_xor(s2, o, 64);
            float r = rsqrtf(s2 * (1.f / DIM) + 1e-6f);
            size_t tok = (size_t)b * NTOK + n0 + tl;
#pragma unroll
            for (int i = 0; i < 6; ++i) {
                int c = lane + 64 * i;
                hOut[tok * DIM + c] = v[i];
                y[tok * DIM + c] = __float2bfloat16((v[i] - mu) * r * g[c] + bta[c]);
            }
        }
    }
}

// ---------------------------------------------------------------------------
// 64x64 bf16 MFMA GEMM, templated BK (64 or 128), single-buffered.
// BK=64 for the M-large GEMMs (QKV, W1): 16 KB LDS -> 8 blocks/CU (R7 showed
// BK=128's 5 blocks/CU loses more TLP than the barrier halving gains).
// BK=128 only where K=1536 amortizes (W2).
// XCD-swizzled block id (T1, bijective: all grids %8==0).
// TRANSOUT: write f32 out[b][c][n] transposed via LDS tile (N must be 384).
// QKV: cols <768 -> bf16 C[M,1152]; cols >=768 (V) -> permuted VT directly.
// ---------------------------------------------------------------------------
template<int BK, bool GELU, bool BF16OUT, bool TRANSOUT, bool QKV>
__global__ __launch_bounds__(256) void gemm_mfma(
    const __hip_bfloat16* __restrict__ A,    // [M,K]
    const __hip_bfloat16* __restrict__ BT,   // [N,K]
    const float* __restrict__ bias,
    const float* __restrict__ res,
    void* __restrict__ Cout,
    int M, int N, int K,
    __hip_bfloat16* __restrict__ vtout) {
    constexpr int NC = BK / 32;
    __shared__ __align__(16) u16 As[NC][64 * 32];
    __shared__ __align__(16) u16 Bs[NC][64 * 32];
    const int nwg = gridDim.x * gridDim.y;
    const int lid = blockIdx.y * gridDim.x + blockIdx.x;
    const int swz = (lid & 7) * (nwg >> 3) + (lid >> 3);
    const int bx = swz % gridDim.x, by = swz / gridDim.x;
    int bm = by * 64, bn = bx * 64;
    int tid = threadIdx.x;
    int w = tid >> 6, l = tid & 63;
    int m0 = (w >> 1) * 32, n0 = (w & 1) * 32;
    int lm = l & 15, ksel = l >> 4;

    int row = tid >> 2, c16 = tid & 3;
    const __hip_bfloat16* ga = A  + (size_t)(bm + row) * K + c16 * 8;
    const __hip_bfloat16* gb = BT + (size_t)(bn + row) * K + c16 * 8;

    f32x4 acc[2][2] = {};
    for (int k0 = 0; k0 < K; k0 += BK) {
#pragma unroll
        for (int c = 0; c < NC; ++c) {
            load_lds16(ga + k0 + c * 32, &As[c][tid * 8]);
            load_lds16(gb + k0 + c * 32, &Bs[c][tid * 8]);
        }
        __syncthreads();
#pragma unroll
        for (int kk = 0; kk < NC; ++kk) {
            bf16x8 af0 = *(const bf16x8*)&As[kk][(m0 +      lm) * 32 + ksel * 8];
            bf16x8 af1 = *(const bf16x8*)&As[kk][(m0 + 16 + lm) * 32 + ksel * 8];
            bf16x8 bf0 = *(const bf16x8*)&Bs[kk][(n0 +      lm) * 32 + ksel * 8];
            bf16x8 bf1 = *(const bf16x8*)&Bs[kk][(n0 + 16 + lm) * 32 + ksel * 8];
            acc[0][0] = __builtin_amdgcn_mfma_f32_16x16x32_bf16(af0, bf0, acc[0][0], 0, 0, 0);
            acc[0][1] = __builtin_amdgcn_mfma_f32_16x16x32_bf16(af0, bf1, acc[0][1], 0, 0, 0);
            acc[1][0] = __builtin_amdgcn_mfma_f32_16x16x32_bf16(af1, bf0, acc[1][0], 0, 0, 0);
            acc[1][1] = __builtin_amdgcn_mfma_f32_16x16x32_bf16(af1, bf1, acc[1][1], 0, 0, 0);
        }
        __syncthreads();
    }

    if constexpr (TRANSOUT) {
        __shared__ float ct[64 * 65];
#pragma unroll
        for (int i = 0; i < 2; ++i)
#pragma unroll
            for (int j = 0; j < 2; ++j)
#pragma unroll
                for (int r = 0; r < 4; ++r) {
                    int ml = m0 + i * 16 + ksel * 4 + r;
                    int cl = n0 + j * 16 + lm;
                    float v = acc[i][j][r];
                    if (bias) v += bias[bn + cl];
                    if (res)  v += res[(size_t)(bm + ml) * N + bn + cl];
                    ct[ml * 65 + cl] = v;
                }
        __syncthreads();
        int bb = bm >> 11, nb = bm & (NTOK - 1);
        float* outp = (float*)Cout + (size_t)bb * DIM * NTOK + nb;
#pragma unroll
        for (int cl = w; cl < 64; cl += 4)
            outp[(size_t)(bn + cl) * NTOK + l] = ct[l * 65 + cl];
    } else {
#pragma unroll
        for (int i = 0; i < 2; ++i)
#pragma unroll
            for (int j = 0; j < 2; ++j)
#pragma unroll
                for (int r = 0; r < 4; ++r) {
                    int rg = bm + m0 + i * 16 + ksel * 4 + r;
                    int cg = bn + n0 + j * 16 + lm;
                    float v = acc[i][j][r];
                    if (bias) v += bias[cg];
                    if (GELU) v = 0.5f * v * (1.f + erff(v * 0.7071067811865475f));
                    if (res)  v += res[(size_t)rg * N + cg];
                    if constexpr (QKV) {
                        if (cg < 768) {
                            ((__hip_bfloat16*)Cout)[(size_t)rg * 1152 + cg] = __float2bfloat16(v);
                        } else {
                            int c = cg - 768, hh = c / 48, dd = c - hh * 48;
                            int bb = rg >> 11, n = rg & (NTOK - 1);
                            int kk = n & 127;
                            int pos = ((kk >> 6) << 6) + ((kk & 15) << 2) + ((kk >> 4) & 3);
                            vtout[((size_t)(bb * NHEAD + hh) * 48 + dd) * 2048
                                  + (n & ~127) + pos] = __float2bfloat16(v);
                        }
                    } else if constexpr (BF16OUT) {
                        ((__hip_bfloat16*)Cout)[(size_t)rg * N + cg] = __float2bfloat16(v);
                    } else {
                        ((float*)Cout)[(size_t)rg * N + cg] = v;
                    }
                }
    }
}

// ---------------------------------------------------------------------------
// wo_ln: fused output-projection + bias + residual + LayerNorm2.
// Tile 16M x 384N (full width -> row statistics in-block), grid 256 = 1/CU.
// BK=64, DOUBLE-BUFFERED staging: this kernel uniquely runs at 1 block/CU
// (no inter-block TLP to hide barrier drains), so loads(t+1) are issued into
// buf^1 before compute(t) and only ONE barrier per K-step remains (R3-verified
// pipeline pattern). LDS 4+96 KB -> still 1 block/CU (grid-limited anyway).
// XOR granule swizzle g^(row&7) (rule-21: inverse-permuted global src, linear
// gload_lds dest, same XOR on read; row==lm mod 8 for A and B reads).
// ---------------------------------------------------------------------------
__global__ __launch_bounds__(256) void wo_ln(
    const __hip_bfloat16* __restrict__ A,    // bufAb [4096][384]
    const __hip_bfloat16* __restrict__ BT,   // WoT   [384][384]
    const float* __restrict__ bo,
    const float* __restrict__ g2, const float* __restrict__ b2,
    float* __restrict__ h,                   // bufH in (old) / out (new)
    __hip_bfloat16* __restrict__ y) {        // bufNb
    __shared__ __align__(16) u16 As[2][16 * 64];    //  4 KB
    __shared__ __align__(16) u16 Bs[2][384 * 64];   // 96 KB
    __shared__ float red[16 * 8];
    const int r0 = blockIdx.x * 16;
    const int tid = threadIdx.x;
    const int w = tid >> 6, l = tid & 63, lm = l & 15, quad = l >> 4;

    // A staging: 128 granules; thread tid<128: row=tid>>3, phys g=tid&7,
    // logical g = phys ^ (row&7)
    const int arow = tid >> 3;
    const int ag = (tid & 7) ^ (arow & 7);
    const __hip_bfloat16* gaA = A + (size_t)(r0 + arow) * DIM + ag * 8;
    const int xr = lm & 7;                       // read-side granule XOR

    // prologue: stage k0=0 into buffer 0
    if (tid < 128) load_lds16(gaA, (char*)As[0] + tid * 16);
#pragma unroll
    for (int i = 0; i < 12; ++i) {
        int idx = tid + i * 256;
        int brow = idx >> 3;
        int bg = (idx & 7) ^ (brow & 7);
        load_lds16(BT + (size_t)brow * DIM + bg * 8, (char*)Bs[0] + idx * 16);
    }
    __syncthreads();

    f32x4 acc[6] = {};
    for (int t = 0; t < 6; ++t) {
        const int cur = t & 1;
        if (t + 1 < 6) {
            const int k1 = (t + 1) * 64;
            if (tid < 128) load_lds16(gaA + k1, (char*)As[cur ^ 1] + tid * 16);
#pragma unroll
            for (int i = 0; i < 12; ++i) {
                int idx = tid + i * 256;
                int brow = idx >> 3;
                int bg = (idx & 7) ^ (brow & 7);
                load_lds16(BT + (size_t)brow * DIM + k1 + bg * 8,
                           (char*)Bs[cur ^ 1] + idx * 16);
            }
        }
#pragma unroll
        for (int kk = 0; kk < 2; ++kk) {
            int goff = ((kk * 4 + quad) ^ xr) * 8;
            bf16x8 af = *(const bf16x8*)&As[cur][lm * 64 + goff];
#pragma unroll
            for (int n = 0; n < 6; ++n) {
                bf16x8 bf = *(const bf16x8*)&Bs[cur][(w * 96 + n * 16 + lm) * 64 + goff];
                acc[n] = __builtin_amdgcn_mfma_f32_16x16x32_bf16(af, bf, acc[n], 0, 0, 0);
            }
        }
        // barrier: next tile's loads resident + all waves done reading cur
        // (iter t+1 overwrites buf cur). Skippable on last iteration.
        if (t + 1 < 6) __syncthreads();
    }

    // epilogue: v = acc + bias + residual; row stats; LN; writes
    float vv[6][4];
    float s1[4] = {0.f, 0.f, 0.f, 0.f}, s2[4] = {0.f, 0.f, 0.f, 0.f};
#pragma unroll
    for (int r = 0; r < 4; ++r) {
        int rg = r0 + quad * 4 + r;
#pragma unroll
        for (int n = 0; n < 6; ++n) {
            int cg = w * 96 + n * 16 + lm;
            float v = acc[n][r] + bo[cg] + h[(size_t)rg * DIM + cg];
            vv[n][r] = v;
            s1[r] += v;
            s2[r] += v * v;
            h[(size_t)rg * DIM + cg] = v;        // new residual state
        }
    }
#pragma unroll
    for (int r = 0; r < 4; ++r) {
#pragma unroll
        for (int o = 8; o; o >>= 1) {
            s1[r] += __shfl_xor(s1[r], o, 64);   // reduces within 16-lane group
            s2[r] += __shfl_xor(s2[r], o, 64);
        }
        if (lm == 0) {
            red[(quad * 4 + r) * 8 + w * 2]     = s1[r];
            red[(quad * 4 + r) * 8 + w * 2 + 1] = s2[r];
        }
    }
    __syncthreads();
#pragma unroll
    for (int r = 0; r < 4; ++r) {
        int lr = quad * 4 + r;
        float S1 = red[lr * 8] + red[lr * 8 + 2] + red[lr * 8 + 4] + red[lr * 8 + 6];
        float S2 = red[lr * 8 + 1] + red[lr * 8 + 3] + red[lr * 8 + 5] + red[lr * 8 + 7];
        float mu = S1 * (1.f / DIM);
        float var = S2 * (1.f / DIM) - mu * mu;
        float rstd = rsqrtf(var + 1e-6f);
        int rg = r0 + lr;
#pragma unroll
        for (int n = 0; n < 6; ++n) {
            int cg = w * 96 + n * 16 + lm;
            y[(size_t)rg * DIM + cg] =
                __float2bfloat16((vv[n][r] - mu) * rstd * g2[cg] + b2[cg]);
        }
    }
}

// ---------------------------------------------------------------------------
// bf16 MFMA flash attention (R4/R6 champion structure: single-buffered K/V,
// T14 reg-prefetch + XCD swizzle; R9's dbuf variant measured -1.4us, reverted).
// ---------------------------------------------------------------------------
#define ATK 128
#define PSTR 136   // row stride in u16; rows 16B-aligned
__global__ __launch_bounds__(512, 4) void attn_mfma(
    const u16* __restrict__ qkv,             // bf16 [TOKS][1152] (Q,K valid)
    const u16* __restrict__ vt,              // bf16 [16][48][2048] (permuted keys)
    __hip_bfloat16* __restrict__ outp) {     // bf16 [TOKS][DIM]
    __shared__ __align__(16) u16 PQ[64 * PSTR];   // Qs (stride 72) then Ps
    __shared__ __align__(16) u16 Ks[128 * 72];
    __shared__ __align__(16) u16 Vs[48 * PSTR];
    const int lid = (blockIdx.z * NHEAD + blockIdx.y) * (NTOK / 64) + blockIdx.x;
    const int swz = (lid & 7) * 64 + (lid >> 3);
    const int q0 = (swz & 31) * 64;
    const int h = (swz >> 5) & 7, b = swz >> 8;
    const int tid = threadIdx.x;
    const int w = tid >> 6, l = tid & 63, lm = l & 15, quad = l >> 4;
    const int qc = w >> 1, kh = w & 1;

    for (int idx = tid; idx < 128; idx += 512) {
        int r = idx >> 1, c = idx & 1;
        *(uint4*)&PQ[r * 72 + 48 + c * 8] = uint4{0, 0, 0, 0};
    }
    for (int idx = tid; idx < 256; idx += 512) {
        int r = idx >> 1, c = idx & 1;
        *(uint4*)&Ks[r * 72 + 48 + c * 8] = uint4{0, 0, 0, 0};
    }
    const u16* qbase = qkv + (size_t)(b * NTOK + q0) * 1152 + h * 48;
    for (int idx = tid; idx < 384; idx += 512) {
        int r = idx / 6, c = idx % 6;
        *(uint4*)&PQ[r * 72 + c * 8] = *(const uint4*)(qbase + (size_t)r * 1152 + c * 8);
    }
    __syncthreads();

    bf16x8 aq0 = *(const bf16x8*)&PQ[(qc * 16 + lm) * 72 +  0 + quad * 8];
    bf16x8 aq1 = *(const bf16x8*)&PQ[(qc * 16 + lm) * 72 + 32 + quad * 8];

    float l_i[4] = {0.f, 0.f, 0.f, 0.f};
    f32x4 o_acc[3] = {};

    const u16* kbase = qkv + (size_t)(b * NTOK) * 1152 + 384 + h * 48;
    const u16* vbase = vt + (size_t)(b * NHEAD + h) * 48 * 2048;
    const float sc2 = 0.14433756729740643f * 1.4426950408889634f;  // scale*log2e

    const int kr0 = tid / 6,  kc0 = tid % 6;
    const int kr1 = (tid + 512) / 6, kc1 = (tid + 512) % 6;
    const int vd0 = tid >> 4, vc0 = tid & 15;
    const int vd1 = (tid + 512) >> 4, vc1 = (tid + 512) & 15;
    const bool two = tid < 256;
    uint4 kp0, kp1, vp0, vp1;

    {
        kp0 = *(const uint4*)(kbase + (size_t)kr0 * 1152 + kc0 * 8);
        vp0 = *(const uint4*)(vbase + (size_t)vd0 * 2048 + vc0 * 8);
        if (two) {
            kp1 = *(const uint4*)(kbase + (size_t)kr1 * 1152 + kc1 * 8);
            vp1 = *(const uint4*)(vbase + (size_t)vd1 * 2048 + vc1 * 8);
        }
    }

    for (int kt = 0; kt < NTOK / ATK; ++kt) {
        __syncthreads();
        *(uint4*)&Ks[kr0 * 72 + kc0 * 8] = kp0;
        *(uint4*)&Vs[vd0 * PSTR + vc0 * 8] = vp0;
        if (two) {
            *(uint4*)&Ks[kr1 * 72 + kc1 * 8] = kp1;
            *(uint4*)&Vs[vd1 * PSTR + vc1 * 8] = vp1;
        }
        __syncthreads();
        if (kt + 1 < NTOK / ATK) {
            const u16* kb = kbase + (size_t)(kt + 1) * ATK * 1152;
            const u16* vb = vbase + (size_t)(kt + 1) * ATK;
            kp0 = *(const uint4*)(kb + (size_t)kr0 * 1152 + kc0 * 8);
            vp0 = *(const uint4*)(vb + (size_t)vd0 * 2048 + vc0 * 8);
            if (two) {
                kp1 = *(const uint4*)(kb + (size_t)kr1 * 1152 + kc1 * 8);
                vp1 = *(const uint4*)(vb + (size_t)vd1 * 2048 + vc1 * 8);
            }
        }

        f32x4 s[4];
#pragma unroll
        for (int ntp = 0; ntp < 4; ++ntp) {
            int nt = kh * 4 + ntp;
            bf16x8 kf0 = *(const bf16x8*)&Ks[(nt * 16 + lm) * 72 +  0 + quad * 8];
            bf16x8 kf1 = *(const bf16x8*)&Ks[(nt * 16 + lm) * 72 + 32 + quad * 8];
            f32x4 t = {};
            t = __builtin_amdgcn_mfma_f32_16x16x32_bf16(aq0, kf0, t, 0, 0, 0);
            t = __builtin_amdgcn_mfma_f32_16x16x32_bf16(aq1, kf1, t, 0, 0, 0);
            s[ntp] = t;
        }

#pragma unroll
        for (int r = 0; r < 4; ++r) {
            u16 pr[4];
#pragma unroll
            for (int ntp = 0; ntp < 4; ++ntp) {
                float p = exp2f(s[ntp][r] * sc2);
                l_i[r] += p;
                bfu cv; cv.h = __float2bfloat16(p);
                pr[ntp] = cv.u;
            }
            *(uint2*)&PQ[(qc * 16 + quad * 4 + r) * PSTR + kh * 64 + lm * 4] =
                *(const uint2*)pr;
        }

#pragma unroll
        for (int ksp = 0; ksp < 2; ++ksp) {
            int ks = kh * 2 + ksp;
            bf16x8 pf = *(const bf16x8*)&PQ[(qc * 16 + lm) * PSTR + ks * 32 + quad * 8];
#pragma unroll
            for (int nt = 0; nt < 3; ++nt) {
                bf16x8 vf = *(const bf16x8*)&Vs[(nt * 16 + lm) * PSTR + ks * 32 + quad * 8];
                o_acc[nt] = __builtin_amdgcn_mfma_f32_16x16x32_bf16(pf, vf, o_acc[nt], 0, 0, 0);
            }
        }
    }

    __syncthreads();
    float* red = (float*)Ks;
    if (kh == 1) {
        f32x4* base = (f32x4*)&red[(qc * 64 + l) * 16];
        base[0] = o_acc[0]; base[1] = o_acc[1]; base[2] = o_acc[2];
        f32x4 lv; lv[0] = l_i[0]; lv[1] = l_i[1]; lv[2] = l_i[2]; lv[3] = l_i[3];
        base[3] = lv;
    }
    __syncthreads();
    if (kh == 0) {
        f32x4* base = (f32x4*)&red[(qc * 64 + l) * 16];
        o_acc[0] += base[0]; o_acc[1] += base[1]; o_acc[2] += base[2];
        f32x4 lv = base[3];
#pragma unroll
        for (int r = 0; r < 4; ++r) {
            float lsum = l_i[r] + lv[r];
#pragma unroll
            for (int o = 8; o; o >>= 1) lsum += __shfl_xor(lsum, o, 64);
            float inv = 1.f / lsum;
#pragma unroll
            for (int nt = 0; nt < 3; ++nt)
                outp[(size_t)(b * NTOK + q0 + qc * 16 + quad * 4 + r) * DIM
                     + h * 48 + nt * 16 + lm]
                    = __float2bfloat16(o_acc[nt][r] * inv);
        }
    }
}

// ---------------------------------------------------------------------------
extern "C" void kernel_launch(void* const* d_in, const int* in_sizes, int n_in,
                              void* d_out, int out_size, void* d_ws, size_t ws_size,
                              hipStream_t stream) {
    const float* x    = (const float*)d_in[0];
    const float* g1   = (const float*)d_in[1];
    const float* b1   = (const float*)d_in[2];
    const float* Wqkv = (const float*)d_in[3];
    const float* Wo   = (const float*)d_in[4];
    const float* bo   = (const float*)d_in[5];
    const float* g2   = (const float*)d_in[6];
    const float* b2   = (const float*)d_in[7];
    const float* W1   = (const float*)d_in[8];
    const float* b1m  = (const float*)d_in[9];
    const float* W2   = (const float*)d_in[10];
    const float* b2m  = (const float*)d_in[11];
    float* out = (float*)d_out;

    char* p = (char*)d_ws;
    float* bufH = (float*)p;                       p += (size_t)TOKS * DIM * 4;      // f32 [4096,384]
    char* qkvp = p;
    __hip_bfloat16* bufQKVb = (__hip_bfloat16*)p;  p += (size_t)TOKS * 3 * DIM * 2;  // bf16 [4096,1152]
    __hip_bfloat16* bufVT   = (__hip_bfloat16*)p;  p += (size_t)TOKS * DIM * 2;      // bf16 [16,48,2048]
    __hip_bfloat16* bufNb   = (__hip_bfloat16*)p;  p += (size_t)TOKS * DIM * 2;      // bf16 [4096,384]
    __hip_bfloat16* bufAb   = (__hip_bfloat16*)p;  p += (size_t)TOKS * DIM * 2;      // bf16 [4096,384]
    __hip_bfloat16* WqkvT   = (__hip_bfloat16*)p;  p += (size_t)3 * DIM * DIM * 2;   // [1152,384]
    __hip_bfloat16* WoT     = (__hip_bfloat16*)p;  p += (size_t)DIM * DIM * 2;       // [384,384]
    __hip_bfloat16* W1T     = (__hip_bfloat16*)p;  p += (size_t)HIDDEN * DIM * 2;    // [1536,384]
    __hip_bfloat16* W2T     = (__hip_bfloat16*)p;  p += (size_t)DIM * HIDDEN * 2;    // [384,1536]
    __hip_bfloat16* bufHIDb = (__hip_bfloat16*)qkvp;  // bf16 [4096,1536] overlays QKV+VT

    // 0. weight transposes + input transpose/LN1 (one dispatch)
    prep<<<1728 + 128, 256, 0, stream>>>(Wqkv, Wo, W1, W2, WqkvT, WoT, W1T, W2T,
                                         x, g1, b1, bufH, bufNb);
    // 1. QKV projection (BK=64, 8 blocks/CU): Q,K -> bufQKVb; V -> bufVT
    gemm_mfma<64, false, true, false, true><<<dim3(3 * DIM / 64, TOKS / 64), 256, 0, stream>>>(
        bufNb, WqkvT, nullptr, nullptr, bufQKVb, TOKS, 3 * DIM, DIM, bufVT);
    // 2. MFMA flash attention -> bf16 (R6 champion structure)
    attn_mfma<<<dim3(NTOK / 64, NHEAD, BATCH), 512, 0, stream>>>(
        (const u16*)bufQKVb, (const u16*)bufVT, bufAb);
    // 3. fused output projection + bias + residual + LN2 (BK=64 + dbuf)
    wo_ln<<<TOKS / 16, 256, 0, stream>>>(bufAb, WoT, bo, g2, b2, bufH, bufNb);
    // 4. MLP up + GELU -> bf16 hidden (BK=64, 8 blocks/CU)
    gemm_mfma<64, true, true, false, false><<<dim3(HIDDEN / 64, TOKS / 64), 256, 0, stream>>>(
        bufNb, W1T, b1m, nullptr, bufHIDb, TOKS, HIDDEN, DIM, nullptr);
    // 5. MLP down + bias + residual -> out (transposed write, f32), BK=128
    gemm_mfma<128, false, false, true, false><<<dim3(DIM / 64, TOKS / 64), 256, 0, stream>>>(
        bufHIDb, W2T, b2m, bufH, out, TOKS, DIM, HIDDEN, nullptr);
}

// Round 11
// 186.351 us; speedup vs baseline: 1.0172x; 1.0172x over previous
//
#include <hip/hip_runtime.h>
#include <hip/hip_bf16.h>
#include <math.h>

#define DIM    384
#define NHEAD  8
#define HDIM   48
#define NTOK   2048              // tokens per batch (8*16*16)
#define BATCH  2
#define TOKS   (BATCH * NTOK)    // 4096
#define HIDDEN 1536

typedef __bf16 bf16x8 __attribute__((ext_vector_type(8)));
typedef float  f32x4  __attribute__((ext_vector_type(4)));
typedef unsigned short u16;

union bfu { __hip_bfloat16 h; u16 u; };

__device__ __forceinline__ void load_lds16(const void* g, void* l) {
    __builtin_amdgcn_global_load_lds(
        (const __attribute__((address_space(1))) void*)g,
        (__attribute__((address_space(3))) void*)l, 16, 0, 0);
}

// ---------------------------------------------------------------------------
// prep: Wqkv cast+transpose (blocks 0..431) + fused input transpose/LN1
// (blocks 432..559). Wo/W1/W2 transposes moved into the QKV dispatch — they
// are not on QKV's critical path and overlap with the GEMM there.
// ---------------------------------------------------------------------------
__global__ __launch_bounds__(256) void prep(
    const float* __restrict__ Wqkv, __hip_bfloat16* __restrict__ WqkvT,
    const float* __restrict__ x, const float* __restrict__ g,
    const float* __restrict__ bta,
    float* __restrict__ hOut, __hip_bfloat16* __restrict__ y) {
    __shared__ __align__(16) char smem[384 * 33 * 4];
    int id = blockIdx.x;
    int tid = threadIdx.x;
    if (id < 432) {
        float (*t)[33] = (float(*)[33])smem;
        const int R = 384, C = 1152, tc = C / 32;
        int i0 = (id / tc) * 32, j0 = (id % tc) * 32;
        int tx = tid & 31, ty = tid >> 5;
#pragma unroll
        for (int k = 0; k < 32; k += 8)
            t[ty + k][tx] = Wqkv[(size_t)(i0 + ty + k) * C + j0 + tx];
        __syncthreads();
#pragma unroll
        for (int k = 0; k < 32; k += 8)
            WqkvT[(size_t)(j0 + ty + k) * R + i0 + tx] = __float2bfloat16(t[tx][ty + k]);
    } else {
        float* t = (float*)smem;
        int id2 = id - 432;
        int n0 = (id2 & 63) * 32, b = id2 >> 6;
        const float* xb = x + (size_t)b * DIM * NTOK;
        for (int idx = tid; idx < 384 * 32; idx += 256) {
            int c = idx >> 5, n = idx & 31;
            t[c * 33 + n] = xb[(size_t)c * NTOK + n0 + n];
        }
        __syncthreads();
        int wid = tid >> 6, lane = tid & 63;
#pragma unroll
        for (int it = 0; it < 8; ++it) {
            int tl = it * 4 + wid;
            float v[6];
            float s = 0.f;
#pragma unroll
            for (int i = 0; i < 6; ++i) { v[i] = t[(lane + 64 * i) * 33 + tl]; s += v[i]; }
#pragma unroll
            for (int o = 32; o; o >>= 1) s += __shfl_xor(s, o, 64);
            float mu = s * (1.f / DIM);
            float s2 = 0.f;
#pragma unroll
            for (int i = 0; i < 6; ++i) { float d = v[i] - mu; s2 += d * d; }
#pragma unroll
            for (int o = 32; o; o >>= 1) s2 += __shfl_xor(s2, o, 64);
            float r = rsqrtf(s2 * (1.f / DIM) + 1e-6f);
            size_t tok = (size_t)b * NTOK + n0 + tl;
#pragma unroll
            for (int i = 0; i < 6; ++i) {
                int c = lane + 64 * i;
                hOut[tok * DIM + c] = v[i];
                y[tok * DIM + c] = __float2bfloat16((v[i] - mu) * r * g[c] + bta[c]);
            }
        }
    }
}

// ---------------------------------------------------------------------------
// qkv_gemm_xpose: blocks 0..1151 = QKV 64x64 GEMM (BK=64, XCD-swizzled,
// Q,K -> C[M,1152]; V -> permuted VT). Blocks 1152..2447 = Wo/W1/W2
// cast+transpose tiles (backfill the GEMM's latency gaps; complete within
// this dispatch, consumed only by later dispatches).
// ---------------------------------------------------------------------------
__global__ __launch_bounds__(256) void qkv_gemm_xpose(
    const __hip_bfloat16* __restrict__ A,    // bufNb [4096][384]
    const __hip_bfloat16* __restrict__ BT,   // WqkvT [1152][384]
    __hip_bfloat16* __restrict__ Cout,       // bf16 [4096][1152]
    __hip_bfloat16* __restrict__ vtout,      // bf16 [16][48][2048]
    const float* __restrict__ Wo, const float* __restrict__ W1,
    const float* __restrict__ W2,
    __hip_bfloat16* __restrict__ WoT, __hip_bfloat16* __restrict__ W1T,
    __hip_bfloat16* __restrict__ W2T) {
    __shared__ __align__(16) u16 As[2][64 * 32];
    __shared__ __align__(16) u16 Bs[2][64 * 32];
    const int lid = blockIdx.x;
    const int tid = threadIdx.x;
    if (lid < 1152) {
        // ---- QKV GEMM (identical to R6 gemm_mfma<64,...,QKV=true>) ----
        const int swz = (lid & 7) * 144 + (lid >> 3);   // 1152%8==0, bijective
        const int bx = swz % 18, by = swz / 18;
        const int bm = by * 64, bn = bx * 64;
        const int K = DIM;
        int w = tid >> 6, l = tid & 63;
        int m0 = (w >> 1) * 32, n0 = (w & 1) * 32;
        int lm = l & 15, ksel = l >> 4;

        int row = tid >> 2, c16 = tid & 3;
        const __hip_bfloat16* ga = A  + (size_t)(bm + row) * K + c16 * 8;
        const __hip_bfloat16* gb = BT + (size_t)(bn + row) * K + c16 * 8;

        f32x4 acc[2][2] = {};
        for (int k0 = 0; k0 < K; k0 += 64) {
#pragma unroll
            for (int c = 0; c < 2; ++c) {
                load_lds16(ga + k0 + c * 32, &As[c][tid * 8]);
                load_lds16(gb + k0 + c * 32, &Bs[c][tid * 8]);
            }
            __syncthreads();
#pragma unroll
            for (int kk = 0; kk < 2; ++kk) {
                bf16x8 af0 = *(const bf16x8*)&As[kk][(m0 +      lm) * 32 + ksel * 8];
                bf16x8 af1 = *(const bf16x8*)&As[kk][(m0 + 16 + lm) * 32 + ksel * 8];
                bf16x8 bf0 = *(const bf16x8*)&Bs[kk][(n0 +      lm) * 32 + ksel * 8];
                bf16x8 bf1 = *(const bf16x8*)&Bs[kk][(n0 + 16 + lm) * 32 + ksel * 8];
                acc[0][0] = __builtin_amdgcn_mfma_f32_16x16x32_bf16(af0, bf0, acc[0][0], 0, 0, 0);
                acc[0][1] = __builtin_amdgcn_mfma_f32_16x16x32_bf16(af0, bf1, acc[0][1], 0, 0, 0);
                acc[1][0] = __builtin_amdgcn_mfma_f32_16x16x32_bf16(af1, bf0, acc[1][0], 0, 0, 0);
                acc[1][1] = __builtin_amdgcn_mfma_f32_16x16x32_bf16(af1, bf1, acc[1][1], 0, 0, 0);
            }
            __syncthreads();
        }
#pragma unroll
        for (int i = 0; i < 2; ++i)
#pragma unroll
            for (int j = 0; j < 2; ++j)
#pragma unroll
                for (int r = 0; r < 4; ++r) {
                    int rg = bm + m0 + i * 16 + ksel * 4 + r;
                    int cg = bn + n0 + j * 16 + lm;
                    float v = acc[i][j][r];
                    if (cg < 768) {
                        Cout[(size_t)rg * 1152 + cg] = __float2bfloat16(v);
                    } else {
                        int c = cg - 768, hh = c / 48, dd = c - hh * 48;
                        int bb = rg >> 11, n = rg & (NTOK - 1);
                        int kk = n & 127;
                        int pos = ((kk >> 6) << 6) + ((kk & 15) << 2) + ((kk >> 4) & 3);
                        vtout[((size_t)(bb * NHEAD + hh) * 48 + dd) * 2048
                              + (n & ~127) + pos] = __float2bfloat16(v);
                    }
                }
    } else {
        // ---- weight cast+transpose tile (32x32), aliased onto As/Bs LDS ----
        float (*t)[33] = (float(*)[33])As;   // 4.2 KB < 8 KB
        int id = lid - 1152;
        const float* src; __hip_bfloat16* dst; int R, C;
        if (id < 144)      {            src = Wo; dst = WoT; R = 384;  C = 384; }
        else if (id < 720) { id -= 144; src = W1; dst = W1T; R = 384;  C = 1536; }
        else               { id -= 720; src = W2; dst = W2T; R = 1536; C = 384; }
        int tc = C / 32;
        int i0 = (id / tc) * 32, j0 = (id % tc) * 32;
        int tx = tid & 31, ty = tid >> 5;
#pragma unroll
        for (int k = 0; k < 32; k += 8)
            t[ty + k][tx] = src[(size_t)(i0 + ty + k) * C + j0 + tx];
        __syncthreads();
#pragma unroll
        for (int k = 0; k < 32; k += 8)
            dst[(size_t)(j0 + ty + k) * R + i0 + tx] = __float2bfloat16(t[tx][ty + k]);
    }
}

// ---------------------------------------------------------------------------
// 64x64 bf16 MFMA GEMM, templated BK (64 or 128), single-buffered.
// BK=64 for W1 (8 blocks/CU); BK=128 for W2 (K=1536 amortizes).
// XCD-swizzled block id (T1, bijective: grids %8==0).
// TRANSOUT: write f32 out[b][c][n] transposed via LDS tile (N must be 384).
// ---------------------------------------------------------------------------
template<int BK, bool GELU, bool BF16OUT, bool TRANSOUT>
__global__ __launch_bounds__(256) void gemm_mfma(
    const __hip_bfloat16* __restrict__ A,    // [M,K]
    const __hip_bfloat16* __restrict__ BT,   // [N,K]
    const float* __restrict__ bias,
    const float* __restrict__ res,
    void* __restrict__ Cout,
    int M, int N, int K) {
    constexpr int NC = BK / 32;
    __shared__ __align__(16) u16 As[NC][64 * 32];
    __shared__ __align__(16) u16 Bs[NC][64 * 32];
    const int nwg = gridDim.x * gridDim.y;
    const int lid = blockIdx.y * gridDim.x + blockIdx.x;
    const int swz = (lid & 7) * (nwg >> 3) + (lid >> 3);
    const int bx = swz % gridDim.x, by = swz / gridDim.x;
    int bm = by * 64, bn = bx * 64;
    int tid = threadIdx.x;
    int w = tid >> 6, l = tid & 63;
    int m0 = (w >> 1) * 32, n0 = (w & 1) * 32;
    int lm = l & 15, ksel = l >> 4;

    int row = tid >> 2, c16 = tid & 3;
    const __hip_bfloat16* ga = A  + (size_t)(bm + row) * K + c16 * 8;
    const __hip_bfloat16* gb = BT + (size_t)(bn + row) * K + c16 * 8;

    f32x4 acc[2][2] = {};
    for (int k0 = 0; k0 < K; k0 += BK) {
#pragma unroll
        for (int c = 0; c < NC; ++c) {
            load_lds16(ga + k0 + c * 32, &As[c][tid * 8]);
            load_lds16(gb + k0 + c * 32, &Bs[c][tid * 8]);
        }
        __syncthreads();
#pragma unroll
        for (int kk = 0; kk < NC; ++kk) {
            bf16x8 af0 = *(const bf16x8*)&As[kk][(m0 +      lm) * 32 + ksel * 8];
            bf16x8 af1 = *(const bf16x8*)&As[kk][(m0 + 16 + lm) * 32 + ksel * 8];
            bf16x8 bf0 = *(const bf16x8*)&Bs[kk][(n0 +      lm) * 32 + ksel * 8];
            bf16x8 bf1 = *(const bf16x8*)&Bs[kk][(n0 + 16 + lm) * 32 + ksel * 8];
            acc[0][0] = __builtin_amdgcn_mfma_f32_16x16x32_bf16(af0, bf0, acc[0][0], 0, 0, 0);
            acc[0][1] = __builtin_amdgcn_mfma_f32_16x16x32_bf16(af0, bf1, acc[0][1], 0, 0, 0);
            acc[1][0] = __builtin_amdgcn_mfma_f32_16x16x32_bf16(af1, bf0, acc[1][0], 0, 0, 0);
            acc[1][1] = __builtin_amdgcn_mfma_f32_16x16x32_bf16(af1, bf1, acc[1][1], 0, 0, 0);
        }
        __syncthreads();
    }

    if constexpr (TRANSOUT) {
        __shared__ float ct[64 * 65];
#pragma unroll
        for (int i = 0; i < 2; ++i)
#pragma unroll
            for (int j = 0; j < 2; ++j)
#pragma unroll
                for (int r = 0; r < 4; ++r) {
                    int ml = m0 + i * 16 + ksel * 4 + r;
                    int cl = n0 + j * 16 + lm;
                    float v = acc[i][j][r];
                    if (bias) v += bias[bn + cl];
                    if (res)  v += res[(size_t)(bm + ml) * N + bn + cl];
                    ct[ml * 65 + cl] = v;
                }
        __syncthreads();
        int bb = bm >> 11, nb = bm & (NTOK - 1);
        float* outp = (float*)Cout + (size_t)bb * DIM * NTOK + nb;
#pragma unroll
        for (int cl = w; cl < 64; cl += 4)
            outp[(size_t)(bn + cl) * NTOK + l] = ct[l * 65 + cl];
    } else {
#pragma unroll
        for (int i = 0; i < 2; ++i)
#pragma unroll
            for (int j = 0; j < 2; ++j)
#pragma unroll
                for (int r = 0; r < 4; ++r) {
                    int rg = bm + m0 + i * 16 + ksel * 4 + r;
                    int cg = bn + n0 + j * 16 + lm;
                    float v = acc[i][j][r];
                    if (bias) v += bias[cg];
                    if (GELU) v = 0.5f * v * (1.f + erff(v * 0.7071067811865475f));
                    if (res)  v += res[(size_t)rg * N + cg];
                    if constexpr (BF16OUT) {
                        ((__hip_bfloat16*)Cout)[(size_t)rg * N + cg] = __float2bfloat16(v);
                    } else {
                        ((float*)Cout)[(size_t)rg * N + cg] = v;
                    }
                }
    }
}

// ---------------------------------------------------------------------------
// wo_ln: fused output-projection + bias + residual + LayerNorm2 (R6 champion:
// BK=64, single-buffered). Tile 16M x 384N, grid 256 = 1/CU. XOR granule
// swizzle g^(row&7) (rule-21: inverse-permuted global src, linear gload_lds
// dest, same XOR on read).
// ---------------------------------------------------------------------------
__global__ __launch_bounds__(256) void wo_ln(
    const __hip_bfloat16* __restrict__ A,    // bufAb [4096][384]
    const __hip_bfloat16* __restrict__ BT,   // WoT   [384][384]
    const float* __restrict__ bo,
    const float* __restrict__ g2, const float* __restrict__ b2,
    float* __restrict__ h,                   // bufH in (old) / out (new)
    __hip_bfloat16* __restrict__ y) {        // bufNb
    __shared__ __align__(16) u16 As[16 * 64];    //  2 KB
    __shared__ __align__(16) u16 Bs[384 * 64];   // 48 KB
    __shared__ float red[16 * 8];
    const int r0 = blockIdx.x * 16;
    const int tid = threadIdx.x;
    const int w = tid >> 6, l = tid & 63, lm = l & 15, quad = l >> 4;

    const int arow = tid >> 3;
    const int ag = (tid & 7) ^ (arow & 7);
    const __hip_bfloat16* gaA = A + (size_t)(r0 + arow) * DIM + ag * 8;
    const int xr = lm & 7;                       // read-side granule XOR

    f32x4 acc[6] = {};
    for (int k0 = 0; k0 < DIM; k0 += 64) {
        if (tid < 128) load_lds16(gaA + k0, (char*)As + tid * 16);
#pragma unroll
        for (int i = 0; i < 12; ++i) {
            int idx = tid + i * 256;             // 0..3071
            int brow = idx >> 3;
            int bg = (idx & 7) ^ (brow & 7);
            load_lds16(BT + (size_t)brow * DIM + k0 + bg * 8, (char*)Bs + idx * 16);
        }
        __syncthreads();
#pragma unroll
        for (int kk = 0; kk < 2; ++kk) {
            int goff = ((kk * 4 + quad) ^ xr) * 8;
            bf16x8 af = *(const bf16x8*)&As[lm * 64 + goff];
#pragma unroll
            for (int n = 0; n < 6; ++n) {
                bf16x8 bf = *(const bf16x8*)&Bs[(w * 96 + n * 16 + lm) * 64 + goff];
                acc[n] = __builtin_amdgcn_mfma_f32_16x16x32_bf16(af, bf, acc[n], 0, 0, 0);
            }
        }
        __syncthreads();
    }

    float vv[6][4];
    float s1[4] = {0.f, 0.f, 0.f, 0.f}, s2[4] = {0.f, 0.f, 0.f, 0.f};
#pragma unroll
    for (int r = 0; r < 4; ++r) {
        int rg = r0 + quad * 4 + r;
#pragma unroll
        for (int n = 0; n < 6; ++n) {
            int cg = w * 96 + n * 16 + lm;
            float v = acc[n][r] + bo[cg] + h[(size_t)rg * DIM + cg];
            vv[n][r] = v;
            s1[r] += v;
            s2[r] += v * v;
            h[(size_t)rg * DIM + cg] = v;        // new residual state
        }
    }
#pragma unroll
    for (int r = 0; r < 4; ++r) {
#pragma unroll
        for (int o = 8; o; o >>= 1) {
            s1[r] += __shfl_xor(s1[r], o, 64);
            s2[r] += __shfl_xor(s2[r], o, 64);
        }
        if (lm == 0) {
            red[(quad * 4 + r) * 8 + w * 2]     = s1[r];
            red[(quad * 4 + r) * 8 + w * 2 + 1] = s2[r];
        }
    }
    __syncthreads();
#pragma unroll
    for (int r = 0; r < 4; ++r) {
        int lr = quad * 4 + r;
        float S1 = red[lr * 8] + red[lr * 8 + 2] + red[lr * 8 + 4] + red[lr * 8 + 6];
        float S2 = red[lr * 8 + 1] + red[lr * 8 + 3] + red[lr * 8 + 5] + red[lr * 8 + 7];
        float mu = S1 * (1.f / DIM);
        float var = S2 * (1.f / DIM) - mu * mu;
        float rstd = rsqrtf(var + 1e-6f);
        int rg = r0 + lr;
#pragma unroll
        for (int n = 0; n < 6; ++n) {
            int cg = w * 96 + n * 16 + lm;
            y[(size_t)rg * DIM + cg] =
                __float2bfloat16((vv[n][r] - mu) * rstd * g2[cg] + b2[cg]);
        }
    }
}

// ---------------------------------------------------------------------------
// bf16 MFMA flash attention (R6 champion: single-buffered K/V, T14
// reg-prefetch + XCD swizzle).
// ---------------------------------------------------------------------------
#define ATK 128
#define PSTR 136   // row stride in u16; rows 16B-aligned
__global__ __launch_bounds__(512, 4) void attn_mfma(
    const u16* __restrict__ qkv,             // bf16 [TOKS][1152] (Q,K valid)
    const u16* __restrict__ vt,              // bf16 [16][48][2048] (permuted keys)
    __hip_bfloat16* __restrict__ outp) {     // bf16 [TOKS][DIM]
    __shared__ __align__(16) u16 PQ[64 * PSTR];   // Qs (stride 72) then Ps
    __shared__ __align__(16) u16 Ks[128 * 72];
    __shared__ __align__(16) u16 Vs[48 * PSTR];
    const int lid = (blockIdx.z * NHEAD + blockIdx.y) * (NTOK / 64) + blockIdx.x;
    const int swz = (lid & 7) * 64 + (lid >> 3);
    const int q0 = (swz & 31) * 64;
    const int h = (swz >> 5) & 7, b = swz >> 8;
    const int tid = threadIdx.x;
    const int w = tid >> 6, l = tid & 63, lm = l & 15, quad = l >> 4;
    const int qc = w >> 1, kh = w & 1;

    for (int idx = tid; idx < 128; idx += 512) {
        int r = idx >> 1, c = idx & 1;
        *(uint4*)&PQ[r * 72 + 48 + c * 8] = uint4{0, 0, 0, 0};
    }
    for (int idx = tid; idx < 256; idx += 512) {
        int r = idx >> 1, c = idx & 1;
        *(uint4*)&Ks[r * 72 + 48 + c * 8] = uint4{0, 0, 0, 0};
    }
    const u16* qbase = qkv + (size_t)(b * NTOK + q0) * 1152 + h * 48;
    for (int idx = tid; idx < 384; idx += 512) {
        int r = idx / 6, c = idx % 6;
        *(uint4*)&PQ[r * 72 + c * 8] = *(const uint4*)(qbase + (size_t)r * 1152 + c * 8);
    }
    __syncthreads();

    bf16x8 aq0 = *(const bf16x8*)&PQ[(qc * 16 + lm) * 72 +  0 + quad * 8];
    bf16x8 aq1 = *(const bf16x8*)&PQ[(qc * 16 + lm) * 72 + 32 + quad * 8];

    float l_i[4] = {0.f, 0.f, 0.f, 0.f};
    f32x4 o_acc[3] = {};

    const u16* kbase = qkv + (size_t)(b * NTOK) * 1152 + 384 + h * 48;
    const u16* vbase = vt + (size_t)(b * NHEAD + h) * 48 * 2048;
    const float sc2 = 0.14433756729740643f * 1.4426950408889634f;  // scale*log2e

    const int kr0 = tid / 6,  kc0 = tid % 6;
    const int kr1 = (tid + 512) / 6, kc1 = (tid + 512) % 6;
    const int vd0 = tid >> 4, vc0 = tid & 15;
    const int vd1 = (tid + 512) >> 4, vc1 = (tid + 512) & 15;
    const bool two = tid < 256;
    uint4 kp0, kp1, vp0, vp1;

    {
        kp0 = *(const uint4*)(kbase + (size_t)kr0 * 1152 + kc0 * 8);
        vp0 = *(const uint4*)(vbase + (size_t)vd0 * 2048 + vc0 * 8);
        if (two) {
            kp1 = *(const uint4*)(kbase + (size_t)kr1 * 1152 + kc1 * 8);
            vp1 = *(const uint4*)(vbase + (size_t)vd1 * 2048 + vc1 * 8);
        }
    }

    for (int kt = 0; kt < NTOK / ATK; ++kt) {
        __syncthreads();
        *(uint4*)&Ks[kr0 * 72 + kc0 * 8] = kp0;
        *(uint4*)&Vs[vd0 * PSTR + vc0 * 8] = vp0;
        if (two) {
            *(uint4*)&Ks[kr1 * 72 + kc1 * 8] = kp1;
            *(uint4*)&Vs[vd1 * PSTR + vc1 * 8] = vp1;
        }
        __syncthreads();
        if (kt + 1 < NTOK / ATK) {
            const u16* kb = kbase + (size_t)(kt + 1) * ATK * 1152;
            const u16* vb = vbase + (size_t)(kt + 1) * ATK;
            kp0 = *(const uint4*)(kb + (size_t)kr0 * 1152 + kc0 * 8);
            vp0 = *(const uint4*)(vb + (size_t)vd0 * 2048 + vc0 * 8);
            if (two) {
                kp1 = *(const uint4*)(kb + (size_t)kr1 * 1152 + kc1 * 8);
                vp1 = *(const uint4*)(vb + (size_t)vd1 * 2048 + vc1 * 8);
            }
        }

        f32x4 s[4];
#pragma unroll
        for (int ntp = 0; ntp < 4; ++ntp) {
            int nt = kh * 4 + ntp;
            bf16x8 kf0 = *(const bf16x8*)&Ks[(nt * 16 + lm) * 72 +  0 + quad * 8];
            bf16x8 kf1 = *(const bf16x8*)&Ks[(nt * 16 + lm) * 72 + 32 + quad * 8];
            f32x4 t = {};
            t = __builtin_amdgcn_mfma_f32_16x16x32_bf16(aq0, kf0, t, 0, 0, 0);
            t = __builtin_amdgcn_mfma_f32_16x16x32_bf16(aq1, kf1, t, 0, 0, 0);
            s[ntp] = t;
        }

#pragma unroll
        for (int r = 0; r < 4; ++r) {
            u16 pr[4];
#pragma unroll
            for (int ntp = 0; ntp < 4; ++ntp) {
                float p = exp2f(s[ntp][r] * sc2);
                l_i[r] += p;
                bfu cv; cv.h = __float2bfloat16(p);
                pr[ntp] = cv.u;
            }
            *(uint2*)&PQ[(qc * 16 + quad * 4 + r) * PSTR + kh * 64 + lm * 4] =
                *(const uint2*)pr;
        }

#pragma unroll
        for (int ksp = 0; ksp < 2; ++ksp) {
            int ks = kh * 2 + ksp;
            bf16x8 pf = *(const bf16x8*)&PQ[(qc * 16 + lm) * PSTR + ks * 32 + quad * 8];
#pragma unroll
            for (int nt = 0; nt < 3; ++nt) {
                bf16x8 vf = *(const bf16x8*)&Vs[(nt * 16 + lm) * PSTR + ks * 32 + quad * 8];
                o_acc[nt] = __builtin_amdgcn_mfma_f32_16x16x32_bf16(pf, vf, o_acc[nt], 0, 0, 0);
            }
        }
    }

    __syncthreads();
    float* red = (float*)Ks;
    if (kh == 1) {
        f32x4* base = (f32x4*)&red[(qc * 64 + l) * 16];
        base[0] = o_acc[0]; base[1] = o_acc[1]; base[2] = o_acc[2];
        f32x4 lv; lv[0] = l_i[0]; lv[1] = l_i[1]; lv[2] = l_i[2]; lv[3] = l_i[3];
        base[3] = lv;
    }
    __syncthreads();
    if (kh == 0) {
        f32x4* base = (f32x4*)&red[(qc * 64 + l) * 16];
        o_acc[0] += base[0]; o_acc[1] += base[1]; o_acc[2] += base[2];
        f32x4 lv = base[3];
#pragma unroll
        for (int r = 0; r < 4; ++r) {
            float lsum = l_i[r] + lv[r];
#pragma unroll
            for (int o = 8; o; o >>= 1) lsum += __shfl_xor(lsum, o, 64);
            float inv = 1.f / lsum;
#pragma unroll
            for (int nt = 0; nt < 3; ++nt)
                outp[(size_t)(b * NTOK + q0 + qc * 16 + quad * 4 + r) * DIM
                     + h * 48 + nt * 16 + lm]
                    = __float2bfloat16(o_acc[nt][r] * inv);
        }
    }
}

// ---------------------------------------------------------------------------
extern "C" void kernel_launch(void* const* d_in, const int* in_sizes, int n_in,
                              void* d_out, int out_size, void* d_ws, size_t ws_size,
                              hipStream_t stream) {
    const float* x    = (const float*)d_in[0];
    const float* g1   = (const float*)d_in[1];
    const float* b1   = (const float*)d_in[2];
    const float* Wqkv = (const float*)d_in[3];
    const float* Wo   = (const float*)d_in[4];
    const float* bo   = (const float*)d_in[5];
    const float* g2   = (const float*)d_in[6];
    const float* b2   = (const float*)d_in[7];
    const float* W1   = (const float*)d_in[8];
    const float* b1m  = (const float*)d_in[9];
    const float* W2   = (const float*)d_in[10];
    const float* b2m  = (const float*)d_in[11];
    float* out = (float*)d_out;

    char* p = (char*)d_ws;
    float* bufH = (float*)p;                       p += (size_t)TOKS * DIM * 4;      // f32 [4096,384]
    char* qkvp = p;
    __hip_bfloat16* bufQKVb = (__hip_bfloat16*)p;  p += (size_t)TOKS * 3 * DIM * 2;  // bf16 [4096,1152]
    __hip_bfloat16* bufVT   = (__hip_bfloat16*)p;  p += (size_t)TOKS * DIM * 2;      // bf16 [16,48,2048]
    __hip_bfloat16* bufNb   = (__hip_bfloat16*)p;  p += (size_t)TOKS * DIM * 2;      // bf16 [4096,384]
    __hip_bfloat16* bufAb   = (__hip_bfloat16*)p;  p += (size_t)TOKS * DIM * 2;      // bf16 [4096,384]
    __hip_bfloat16* WqkvT   = (__hip_bfloat16*)p;  p += (size_t)3 * DIM * DIM * 2;   // [1152,384]
    __hip_bfloat16* WoT     = (__hip_bfloat16*)p;  p += (size_t)DIM * DIM * 2;       // [384,384]
    __hip_bfloat16* W1T     = (__hip_bfloat16*)p;  p += (size_t)HIDDEN * DIM * 2;    // [1536,384]
    __hip_bfloat16* W2T     = (__hip_bfloat16*)p;  p += (size_t)DIM * HIDDEN * 2;    // [384,1536]
    __hip_bfloat16* bufHIDb = (__hip_bfloat16*)qkvp;  // bf16 [4096,1536] overlays QKV+VT

    // 0. Wqkv transpose + input transpose/LN1 (critical path only)
    prep<<<432 + 128, 256, 0, stream>>>(Wqkv, WqkvT, x, g1, b1, bufH, bufNb);
    // 1. QKV projection (BK=64, swizzled) + Wo/W1/W2 transposes backfilled
    qkv_gemm_xpose<<<1152 + 1296, 256, 0, stream>>>(
        bufNb, WqkvT, bufQKVb, bufVT, Wo, W1, W2, WoT, W1T, W2T);
    // 2. MFMA flash attention -> bf16 (R6 champion structure)
    attn_mfma<<<dim3(NTOK / 64, NHEAD, BATCH), 512, 0, stream>>>(
        (const u16*)bufQKVb, (const u16*)bufVT, bufAb);
    // 3. fused output projection + bias + residual + LN2 (R6 champion)
    wo_ln<<<TOKS / 16, 256, 0, stream>>>(bufAb, WoT, bo, g2, b2, bufH, bufNb);
    // 4. MLP up + GELU -> bf16 hidden (BK=64, 8 blocks/CU)
    gemm_mfma<64, true, true, false><<<dim3(HIDDEN / 64, TOKS / 64), 256, 0, stream>>>(
        bufNb, W1T, b1m, nullptr, bufHIDb, TOKS, HIDDEN, DIM);
    // 5. MLP down + bias + residual -> out (transposed write, f32), BK=128
    gemm_mfma<128, false, false, true><<<dim3(DIM / 64, TOKS / 64), 256, 0, stream>>>(
        bufHIDb, W2T, b2m, bufH, out, TOKS, DIM, HIDDEN);
}

// Round 12
// 177.646 us; speedup vs baseline: 1.0671x; 1.0490x over previous
//
#include <hip/hip_runtime.h>
#include <hip/hip_bf16.h>
#include <math.h>

#define DIM    384
#define NHEAD  8
#define HDIM   48
#define NTOK   2048              // tokens per batch (8*16*16)
#define BATCH  2
#define TOKS   (BATCH * NTOK)    // 4096
#define HIDDEN 1536

typedef __bf16 bf16x8 __attribute__((ext_vector_type(8)));
typedef float  f32x4  __attribute__((ext_vector_type(4)));
typedef unsigned short u16;

union bfu { __hip_bfloat16 h; u16 u; };

__device__ __forceinline__ void load_lds16(const void* g, void* l) {
    __builtin_amdgcn_global_load_lds(
        (const __attribute__((address_space(1))) void*)g,
        (__attribute__((address_space(3))) void*)l, 16, 0, 0);
}

// ---------------------------------------------------------------------------
// prep: Wqkv cast+transpose (blocks 0..431) + fused input transpose/LN1
// (blocks 432..559). Wo/W1/W2 transposes live in the QKV dispatch (R11).
// ---------------------------------------------------------------------------
__global__ __launch_bounds__(256) void prep(
    const float* __restrict__ Wqkv, __hip_bfloat16* __restrict__ WqkvT,
    const float* __restrict__ x, const float* __restrict__ g,
    const float* __restrict__ bta,
    float* __restrict__ hOut, __hip_bfloat16* __restrict__ y) {
    __shared__ __align__(16) char smem[384 * 33 * 4];
    int id = blockIdx.x;
    int tid = threadIdx.x;
    if (id < 432) {
        float (*t)[33] = (float(*)[33])smem;
        const int R = 384, C = 1152, tc = C / 32;
        int i0 = (id / tc) * 32, j0 = (id % tc) * 32;
        int tx = tid & 31, ty = tid >> 5;
#pragma unroll
        for (int k = 0; k < 32; k += 8)
            t[ty + k][tx] = Wqkv[(size_t)(i0 + ty + k) * C + j0 + tx];
        __syncthreads();
#pragma unroll
        for (int k = 0; k < 32; k += 8)
            WqkvT[(size_t)(j0 + ty + k) * R + i0 + tx] = __float2bfloat16(t[tx][ty + k]);
    } else {
        float* t = (float*)smem;
        int id2 = id - 432;
        int n0 = (id2 & 63) * 32, b = id2 >> 6;
        const float* xb = x + (size_t)b * DIM * NTOK;
        for (int idx = tid; idx < 384 * 32; idx += 256) {
            int c = idx >> 5, n = idx & 31;
            t[c * 33 + n] = xb[(size_t)c * NTOK + n0 + n];
        }
        __syncthreads();
        int wid = tid >> 6, lane = tid & 63;
#pragma unroll
        for (int it = 0; it < 8; ++it) {
            int tl = it * 4 + wid;
            float v[6];
            float s = 0.f;
#pragma unroll
            for (int i = 0; i < 6; ++i) { v[i] = t[(lane + 64 * i) * 33 + tl]; s += v[i]; }
#pragma unroll
            for (int o = 32; o; o >>= 1) s += __shfl_xor(s, o, 64);
            float mu = s * (1.f / DIM);
            float s2 = 0.f;
#pragma unroll
            for (int i = 0; i < 6; ++i) { float d = v[i] - mu; s2 += d * d; }
#pragma unroll
            for (int o = 32; o; o >>= 1) s2 += __shfl_xor(s2, o, 64);
            float r = rsqrtf(s2 * (1.f / DIM) + 1e-6f);
            size_t tok = (size_t)b * NTOK + n0 + tl;
#pragma unroll
            for (int i = 0; i < 6; ++i) {
                int c = lane + 64 * i;
                hOut[tok * DIM + c] = v[i];
                y[tok * DIM + c] = __float2bfloat16((v[i] - mu) * r * g[c] + bta[c]);
            }
        }
    }
}

// ---------------------------------------------------------------------------
// qkv_gemm_xpose: blocks 0..1151 = QKV 64x64 GEMM (BK=64, XCD-swizzled,
// Q,K -> C[M,1152]; V -> permuted VT). Blocks 1152..2447 = Wo/W1/W2
// cast+transpose tiles (backfill the GEMM's latency gaps; R11 technique).
// ---------------------------------------------------------------------------
__global__ __launch_bounds__(256) void qkv_gemm_xpose(
    const __hip_bfloat16* __restrict__ A,    // bufNb [4096][384]
    const __hip_bfloat16* __restrict__ BT,   // WqkvT [1152][384]
    __hip_bfloat16* __restrict__ Cout,       // bf16 [4096][1152]
    __hip_bfloat16* __restrict__ vtout,      // bf16 [16][48][2048]
    const float* __restrict__ Wo, const float* __restrict__ W1,
    const float* __restrict__ W2,
    __hip_bfloat16* __restrict__ WoT, __hip_bfloat16* __restrict__ W1T,
    __hip_bfloat16* __restrict__ W2T) {
    __shared__ __align__(16) u16 As[2][64 * 32];
    __shared__ __align__(16) u16 Bs[2][64 * 32];
    const int lid = blockIdx.x;
    const int tid = threadIdx.x;
    if (lid < 1152) {
        const int swz = (lid & 7) * 144 + (lid >> 3);   // 1152%8==0, bijective
        const int bx = swz % 18, by = swz / 18;
        const int bm = by * 64, bn = bx * 64;
        const int K = DIM;
        int w = tid >> 6, l = tid & 63;
        int m0 = (w >> 1) * 32, n0 = (w & 1) * 32;
        int lm = l & 15, ksel = l >> 4;

        int row = tid >> 2, c16 = tid & 3;
        const __hip_bfloat16* ga = A  + (size_t)(bm + row) * K + c16 * 8;
        const __hip_bfloat16* gb = BT + (size_t)(bn + row) * K + c16 * 8;

        f32x4 acc[2][2] = {};
        for (int k0 = 0; k0 < K; k0 += 64) {
#pragma unroll
            for (int c = 0; c < 2; ++c) {
                load_lds16(ga + k0 + c * 32, &As[c][tid * 8]);
                load_lds16(gb + k0 + c * 32, &Bs[c][tid * 8]);
            }
            __syncthreads();
#pragma unroll
            for (int kk = 0; kk < 2; ++kk) {
                bf16x8 af0 = *(const bf16x8*)&As[kk][(m0 +      lm) * 32 + ksel * 8];
                bf16x8 af1 = *(const bf16x8*)&As[kk][(m0 + 16 + lm) * 32 + ksel * 8];
                bf16x8 bf0 = *(const bf16x8*)&Bs[kk][(n0 +      lm) * 32 + ksel * 8];
                bf16x8 bf1 = *(const bf16x8*)&Bs[kk][(n0 + 16 + lm) * 32 + ksel * 8];
                acc[0][0] = __builtin_amdgcn_mfma_f32_16x16x32_bf16(af0, bf0, acc[0][0], 0, 0, 0);
                acc[0][1] = __builtin_amdgcn_mfma_f32_16x16x32_bf16(af0, bf1, acc[0][1], 0, 0, 0);
                acc[1][0] = __builtin_amdgcn_mfma_f32_16x16x32_bf16(af1, bf0, acc[1][0], 0, 0, 0);
                acc[1][1] = __builtin_amdgcn_mfma_f32_16x16x32_bf16(af1, bf1, acc[1][1], 0, 0, 0);
            }
            __syncthreads();
        }
#pragma unroll
        for (int i = 0; i < 2; ++i)
#pragma unroll
            for (int j = 0; j < 2; ++j)
#pragma unroll
                for (int r = 0; r < 4; ++r) {
                    int rg = bm + m0 + i * 16 + ksel * 4 + r;
                    int cg = bn + n0 + j * 16 + lm;
                    float v = acc[i][j][r];
                    if (cg < 768) {
                        Cout[(size_t)rg * 1152 + cg] = __float2bfloat16(v);
                    } else {
                        int c = cg - 768, hh = c / 48, dd = c - hh * 48;
                        int bb = rg >> 11, n = rg & (NTOK - 1);
                        int kk = n & 127;
                        int pos = ((kk >> 6) << 6) + ((kk & 15) << 2) + ((kk >> 4) & 3);
                        vtout[((size_t)(bb * NHEAD + hh) * 48 + dd) * 2048
                              + (n & ~127) + pos] = __float2bfloat16(v);
                    }
                }
    } else {
        float (*t)[33] = (float(*)[33])As;   // 4.2 KB < 8 KB
        int id = lid - 1152;
        const float* src; __hip_bfloat16* dst; int R, C;
        if (id < 144)      {            src = Wo; dst = WoT; R = 384;  C = 384; }
        else if (id < 720) { id -= 144; src = W1; dst = W1T; R = 384;  C = 1536; }
        else               { id -= 720; src = W2; dst = W2T; R = 1536; C = 384; }
        int tc = C / 32;
        int i0 = (id / tc) * 32, j0 = (id % tc) * 32;
        int tx = tid & 31, ty = tid >> 5;
#pragma unroll
        for (int k = 0; k < 32; k += 8)
            t[ty + k][tx] = src[(size_t)(i0 + ty + k) * C + j0 + tx];
        __syncthreads();
#pragma unroll
        for (int k = 0; k < 32; k += 8)
            dst[(size_t)(j0 + ty + k) * R + i0 + tx] = __float2bfloat16(t[tx][ty + k]);
    }
}

// ---------------------------------------------------------------------------
// 64x64 bf16 MFMA GEMM (BK=64, single-buffered) — used for W1 (MLP up).
// XCD-swizzled block id (T1, bijective: grid %8==0).
// ---------------------------------------------------------------------------
template<int BK, bool GELU>
__global__ __launch_bounds__(256) void gemm_mfma(
    const __hip_bfloat16* __restrict__ A,    // [M,K]
    const __hip_bfloat16* __restrict__ BT,   // [N,K]
    const float* __restrict__ bias,
    __hip_bfloat16* __restrict__ Cout,
    int M, int N, int K) {
    constexpr int NC = BK / 32;
    __shared__ __align__(16) u16 As[NC][64 * 32];
    __shared__ __align__(16) u16 Bs[NC][64 * 32];
    const int nwg = gridDim.x * gridDim.y;
    const int lid = blockIdx.y * gridDim.x + blockIdx.x;
    const int swz = (lid & 7) * (nwg >> 3) + (lid >> 3);
    const int bx = swz % gridDim.x, by = swz / gridDim.x;
    int bm = by * 64, bn = bx * 64;
    int tid = threadIdx.x;
    int w = tid >> 6, l = tid & 63;
    int m0 = (w >> 1) * 32, n0 = (w & 1) * 32;
    int lm = l & 15, ksel = l >> 4;

    int row = tid >> 2, c16 = tid & 3;
    const __hip_bfloat16* ga = A  + (size_t)(bm + row) * K + c16 * 8;
    const __hip_bfloat16* gb = BT + (size_t)(bn + row) * K + c16 * 8;

    f32x4 acc[2][2] = {};
    for (int k0 = 0; k0 < K; k0 += BK) {
#pragma unroll
        for (int c = 0; c < NC; ++c) {
            load_lds16(ga + k0 + c * 32, &As[c][tid * 8]);
            load_lds16(gb + k0 + c * 32, &Bs[c][tid * 8]);
        }
        __syncthreads();
#pragma unroll
        for (int kk = 0; kk < NC; ++kk) {
            bf16x8 af0 = *(const bf16x8*)&As[kk][(m0 +      lm) * 32 + ksel * 8];
            bf16x8 af1 = *(const bf16x8*)&As[kk][(m0 + 16 + lm) * 32 + ksel * 8];
            bf16x8 bf0 = *(const bf16x8*)&Bs[kk][(n0 +      lm) * 32 + ksel * 8];
            bf16x8 bf1 = *(const bf16x8*)&Bs[kk][(n0 + 16 + lm) * 32 + ksel * 8];
            acc[0][0] = __builtin_amdgcn_mfma_f32_16x16x32_bf16(af0, bf0, acc[0][0], 0, 0, 0);
            acc[0][1] = __builtin_amdgcn_mfma_f32_16x16x32_bf16(af0, bf1, acc[0][1], 0, 0, 0);
            acc[1][0] = __builtin_amdgcn_mfma_f32_16x16x32_bf16(af1, bf0, acc[1][0], 0, 0, 0);
            acc[1][1] = __builtin_amdgcn_mfma_f32_16x16x32_bf16(af1, bf1, acc[1][1], 0, 0, 0);
        }
        __syncthreads();
    }

#pragma unroll
    for (int i = 0; i < 2; ++i)
#pragma unroll
        for (int j = 0; j < 2; ++j)
#pragma unroll
            for (int r = 0; r < 4; ++r) {
                int rg = bm + m0 + i * 16 + ksel * 4 + r;
                int cg = bn + n0 + j * 16 + lm;
                float v = acc[i][j][r];
                if (bias) v += bias[cg];
                if (GELU) v = 0.5f * v * (1.f + erff(v * 0.7071067811865475f));
                Cout[(size_t)rg * N + cg] = __float2bfloat16(v);
            }
}

// ---------------------------------------------------------------------------
// w2_gemm: MLP down + bias + residual -> transposed f32 out. 32x64 tiles ->
// 768 blocks = 3 BALANCED rounds/CU (the old 64x64 grid was 384 = 1.5/CU,
// the only load-imbalanced dispatch left). BK=128, identical k-order to the
// old W2 (bit-identical output). 128-col LDS rows would be a 16-way bank
// conflict; rule-21 XOR granule swizzle (g = p ^ (row&7) on the global src,
// same XOR on ds_read; frag rows == lm mod 8 -> per-lane const read XOR).
// LDS 32.3 KB -> 5 blocks/CU capacity >= 3 resident needed.
// ---------------------------------------------------------------------------
__global__ __launch_bounds__(256) void w2_gemm(
    const __hip_bfloat16* __restrict__ A,    // bufHIDb [4096][1536]
    const __hip_bfloat16* __restrict__ BT,   // W2T [384][1536]
    const float* __restrict__ bias,          // b2m
    const float* __restrict__ res,           // bufH f32 [4096][384]
    float* __restrict__ outp) {              // out f32 [2][384][2048]
    __shared__ __align__(16) u16 As[32 * 128];   //  8 KB
    __shared__ __align__(16) u16 Bs[64 * 128];   // 16 KB
    __shared__ float ct[32 * 65];                // 8.3 KB
    const int K = HIDDEN, N = DIM;
    const int nwg = gridDim.x * gridDim.y;       // 768
    const int lid = blockIdx.y * gridDim.x + blockIdx.x;
    const int swz = (lid & 7) * (nwg >> 3) + (lid >> 3);
    const int bx = swz % gridDim.x, by = swz / gridDim.x;
    const int bm = by * 32, bn = bx * 64;
    const int tid = threadIdx.x;
    const int w = tid >> 6, l = tid & 63;
    const int n0 = w * 16;
    const int lm = l & 15, ksel = l >> 4;
    const int xr = lm & 7;                       // read-side granule XOR

    f32x4 acc[2] = {};
    for (int k0 = 0; k0 < K; k0 += 128) {
        // A: 32 rows x 16 granules = 512, 2/thread; B: 64 x 16 = 1024, 4/thread
#pragma unroll
        for (int i = 0; i < 2; ++i) {
            int idx = tid + i * 256;
            int row = idx >> 4, p = idx & 15;
            int g = p ^ (row & 7);
            load_lds16(A + (size_t)(bm + row) * K + k0 + g * 8, (char*)As + idx * 16);
        }
#pragma unroll
        for (int i = 0; i < 4; ++i) {
            int idx = tid + i * 256;
            int row = idx >> 4, p = idx & 15;
            int g = p ^ (row & 7);
            load_lds16(BT + (size_t)(bn + row) * K + k0 + g * 8, (char*)Bs + idx * 16);
        }
        __syncthreads();
#pragma unroll
        for (int kk = 0; kk < 4; ++kk) {
            int gq = ((kk * 4 + ksel) ^ xr) * 8;
            bf16x8 af0 = *(const bf16x8*)&As[lm        * 128 + gq];
            bf16x8 af1 = *(const bf16x8*)&As[(16 + lm) * 128 + gq];
            bf16x8 bf  = *(const bf16x8*)&Bs[(n0 + lm) * 128 + gq];
            acc[0] = __builtin_amdgcn_mfma_f32_16x16x32_bf16(af0, bf, acc[0], 0, 0, 0);
            acc[1] = __builtin_amdgcn_mfma_f32_16x16x32_bf16(af1, bf, acc[1], 0, 0, 0);
        }
        __syncthreads();
    }

    // epilogue: bias + residual into ct, then transposed write
#pragma unroll
    for (int m = 0; m < 2; ++m)
#pragma unroll
        for (int r = 0; r < 4; ++r) {
            int ml = m * 16 + ksel * 4 + r;
            int cl = n0 + lm;
            float v = acc[m][r] + bias[bn + cl]
                    + res[(size_t)(bm + ml) * N + bn + cl];
            ct[ml * 65 + cl] = v;
        }
    __syncthreads();
    int bb = bm >> 11, nb = bm & (NTOK - 1);
    float* op = outp + (size_t)bb * DIM * NTOK + nb;
#pragma unroll
    for (int cc = w * 2; cc < 64; cc += 8) {
        int cl = cc + (l >> 5), rw = l & 31;
        op[(size_t)(bn + cl) * NTOK + rw] = ct[rw * 65 + cl];
    }
}

// ---------------------------------------------------------------------------
// wo_ln: fused output-projection + bias + residual + LayerNorm2 (R6 champion:
// BK=64, single-buffered). Tile 16M x 384N, grid 256 = 1/CU. XOR granule
// swizzle g^(row&7) (rule-21).
// ---------------------------------------------------------------------------
__global__ __launch_bounds__(256) void wo_ln(
    const __hip_bfloat16* __restrict__ A,    // bufAb [4096][384]
    const __hip_bfloat16* __restrict__ BT,   // WoT   [384][384]
    const float* __restrict__ bo,
    const float* __restrict__ g2, const float* __restrict__ b2,
    float* __restrict__ h,                   // bufH in (old) / out (new)
    __hip_bfloat16* __restrict__ y) {        // bufNb
    __shared__ __align__(16) u16 As[16 * 64];    //  2 KB
    __shared__ __align__(16) u16 Bs[384 * 64];   // 48 KB
    __shared__ float red[16 * 8];
    const int r0 = blockIdx.x * 16;
    const int tid = threadIdx.x;
    const int w = tid >> 6, l = tid & 63, lm = l & 15, quad = l >> 4;

    const int arow = tid >> 3;
    const int ag = (tid & 7) ^ (arow & 7);
    const __hip_bfloat16* gaA = A + (size_t)(r0 + arow) * DIM + ag * 8;
    const int xr = lm & 7;                       // read-side granule XOR

    f32x4 acc[6] = {};
    for (int k0 = 0; k0 < DIM; k0 += 64) {
        if (tid < 128) load_lds16(gaA + k0, (char*)As + tid * 16);
#pragma unroll
        for (int i = 0; i < 12; ++i) {
            int idx = tid + i * 256;             // 0..3071
            int brow = idx >> 3;
            int bg = (idx & 7) ^ (brow & 7);
            load_lds16(BT + (size_t)brow * DIM + k0 + bg * 8, (char*)Bs + idx * 16);
        }
        __syncthreads();
#pragma unroll
        for (int kk = 0; kk < 2; ++kk) {
            int goff = ((kk * 4 + quad) ^ xr) * 8;
            bf16x8 af = *(const bf16x8*)&As[lm * 64 + goff];
#pragma unroll
            for (int n = 0; n < 6; ++n) {
                bf16x8 bf = *(const bf16x8*)&Bs[(w * 96 + n * 16 + lm) * 64 + goff];
                acc[n] = __builtin_amdgcn_mfma_f32_16x16x32_bf16(af, bf, acc[n], 0, 0, 0);
            }
        }
        __syncthreads();
    }

    float vv[6][4];
    float s1[4] = {0.f, 0.f, 0.f, 0.f}, s2[4] = {0.f, 0.f, 0.f, 0.f};
#pragma unroll
    for (int r = 0; r < 4; ++r) {
        int rg = r0 + quad * 4 + r;
#pragma unroll
        for (int n = 0; n < 6; ++n) {
            int cg = w * 96 + n * 16 + lm;
            float v = acc[n][r] + bo[cg] + h[(size_t)rg * DIM + cg];
            vv[n][r] = v;
            s1[r] += v;
            s2[r] += v * v;
            h[(size_t)rg * DIM + cg] = v;        // new residual state
        }
    }
#pragma unroll
    for (int r = 0; r < 4; ++r) {
#pragma unroll
        for (int o = 8; o; o >>= 1) {
            s1[r] += __shfl_xor(s1[r], o, 64);
            s2[r] += __shfl_xor(s2[r], o, 64);
        }
        if (lm == 0) {
            red[(quad * 4 + r) * 8 + w * 2]     = s1[r];
            red[(quad * 4 + r) * 8 + w * 2 + 1] = s2[r];
        }
    }
    __syncthreads();
#pragma unroll
    for (int r = 0; r < 4; ++r) {
        int lr = quad * 4 + r;
        float S1 = red[lr * 8] + red[lr * 8 + 2] + red[lr * 8 + 4] + red[lr * 8 + 6];
        float S2 = red[lr * 8 + 1] + red[lr * 8 + 3] + red[lr * 8 + 5] + red[lr * 8 + 7];
        float mu = S1 * (1.f / DIM);
        float var = S2 * (1.f / DIM) - mu * mu;
        float rstd = rsqrtf(var + 1e-6f);
        int rg = r0 + lr;
#pragma unroll
        for (int n = 0; n < 6; ++n) {
            int cg = w * 96 + n * 16 + lm;
            y[(size_t)rg * DIM + cg] =
                __float2bfloat16((vv[n][r] - mu) * rstd * g2[cg] + b2[cg]);
        }
    }
}

// ---------------------------------------------------------------------------
// bf16 MFMA flash attention (R6 champion: single-buffered K/V, T14
// reg-prefetch + XCD swizzle).
// ---------------------------------------------------------------------------
#define ATK 128
#define PSTR 136   // row stride in u16; rows 16B-aligned
__global__ __launch_bounds__(512, 4) void attn_mfma(
    const u16* __restrict__ qkv,             // bf16 [TOKS][1152] (Q,K valid)
    const u16* __restrict__ vt,              // bf16 [16][48][2048] (permuted keys)
    __hip_bfloat16* __restrict__ outp) {     // bf16 [TOKS][DIM]
    __shared__ __align__(16) u16 PQ[64 * PSTR];   // Qs (stride 72) then Ps
    __shared__ __align__(16) u16 Ks[128 * 72];
    __shared__ __align__(16) u16 Vs[48 * PSTR];
    const int lid = (blockIdx.z * NHEAD + blockIdx.y) * (NTOK / 64) + blockIdx.x;
    const int swz = (lid & 7) * 64 + (lid >> 3);
    const int q0 = (swz & 31) * 64;
    const int h = (swz >> 5) & 7, b = swz >> 8;
    const int tid = threadIdx.x;
    const int w = tid >> 6, l = tid & 63, lm = l & 15, quad = l >> 4;
    const int qc = w >> 1, kh = w & 1;

    for (int idx = tid; idx < 128; idx += 512) {
        int r = idx >> 1, c = idx & 1;
        *(uint4*)&PQ[r * 72 + 48 + c * 8] = uint4{0, 0, 0, 0};
    }
    for (int idx = tid; idx < 256; idx += 512) {
        int r = idx >> 1, c = idx & 1;
        *(uint4*)&Ks[r * 72 + 48 + c * 8] = uint4{0, 0, 0, 0};
    }
    const u16* qbase = qkv + (size_t)(b * NTOK + q0) * 1152 + h * 48;
    for (int idx = tid; idx < 384; idx += 512) {
        int r = idx / 6, c = idx % 6;
        *(uint4*)&PQ[r * 72 + c * 8] = *(const uint4*)(qbase + (size_t)r * 1152 + c * 8);
    }
    __syncthreads();

    bf16x8 aq0 = *(const bf16x8*)&PQ[(qc * 16 + lm) * 72 +  0 + quad * 8];
    bf16x8 aq1 = *(const bf16x8*)&PQ[(qc * 16 + lm) * 72 + 32 + quad * 8];

    float l_i[4] = {0.f, 0.f, 0.f, 0.f};
    f32x4 o_acc[3] = {};

    const u16* kbase = qkv + (size_t)(b * NTOK) * 1152 + 384 + h * 48;
    const u16* vbase = vt + (size_t)(b * NHEAD + h) * 48 * 2048;
    const float sc2 = 0.14433756729740643f * 1.4426950408889634f;  // scale*log2e

    const int kr0 = tid / 6,  kc0 = tid % 6;
    const int kr1 = (tid + 512) / 6, kc1 = (tid + 512) % 6;
    const int vd0 = tid >> 4, vc0 = tid & 15;
    const int vd1 = (tid + 512) >> 4, vc1 = (tid + 512) & 15;
    const bool two = tid < 256;
    uint4 kp0, kp1, vp0, vp1;

    {
        kp0 = *(const uint4*)(kbase + (size_t)kr0 * 1152 + kc0 * 8);
        vp0 = *(const uint4*)(vbase + (size_t)vd0 * 2048 + vc0 * 8);
        if (two) {
            kp1 = *(const uint4*)(kbase + (size_t)kr1 * 1152 + kc1 * 8);
            vp1 = *(const uint4*)(vbase + (size_t)vd1 * 2048 + vc1 * 8);
        }
    }

    for (int kt = 0; kt < NTOK / ATK; ++kt) {
        __syncthreads();
        *(uint4*)&Ks[kr0 * 72 + kc0 * 8] = kp0;
        *(uint4*)&Vs[vd0 * PSTR + vc0 * 8] = vp0;
        if (two) {
            *(uint4*)&Ks[kr1 * 72 + kc1 * 8] = kp1;
            *(uint4*)&Vs[vd1 * PSTR + vc1 * 8] = vp1;
        }
        __syncthreads();
        if (kt + 1 < NTOK / ATK) {
            const u16* kb = kbase + (size_t)(kt + 1) * ATK * 1152;
            const u16* vb = vbase + (size_t)(kt + 1) * ATK;
            kp0 = *(const uint4*)(kb + (size_t)kr0 * 1152 + kc0 * 8);
            vp0 = *(const uint4*)(vb + (size_t)vd0 * 2048 + vc0 * 8);
            if (two) {
                kp1 = *(const uint4*)(kb + (size_t)kr1 * 1152 + kc1 * 8);
                vp1 = *(const uint4*)(vb + (size_t)vd1 * 2048 + vc1 * 8);
            }
        }

        f32x4 s[4];
#pragma unroll
        for (int ntp = 0; ntp < 4; ++ntp) {
            int nt = kh * 4 + ntp;
            bf16x8 kf0 = *(const bf16x8*)&Ks[(nt * 16 + lm) * 72 +  0 + quad * 8];
            bf16x8 kf1 = *(const bf16x8*)&Ks[(nt * 16 + lm) * 72 + 32 + quad * 8];
            f32x4 t = {};
            t = __builtin_amdgcn_mfma_f32_16x16x32_bf16(aq0, kf0, t, 0, 0, 0);
            t = __builtin_amdgcn_mfma_f32_16x16x32_bf16(aq1, kf1, t, 0, 0, 0);
            s[ntp] = t;
        }

#pragma unroll
        for (int r = 0; r < 4; ++r) {
            u16 pr[4];
#pragma unroll
            for (int ntp = 0; ntp < 4; ++ntp) {
                float p = exp2f(s[ntp][r] * sc2);
                l_i[r] += p;
                bfu cv; cv.h = __float2bfloat16(p);
                pr[ntp] = cv.u;
            }
            *(uint2*)&PQ[(qc * 16 + quad * 4 + r) * PSTR + kh * 64 + lm * 4] =
                *(const uint2*)pr;
        }

#pragma unroll
        for (int ksp = 0; ksp < 2; ++ksp) {
            int ks = kh * 2 + ksp;
            bf16x8 pf = *(const bf16x8*)&PQ[(qc * 16 + lm) * PSTR + ks * 32 + quad * 8];
#pragma unroll
            for (int nt = 0; nt < 3; ++nt) {
                bf16x8 vf = *(const bf16x8*)&Vs[(nt * 16 + lm) * PSTR + ks * 32 + quad * 8];
                o_acc[nt] = __builtin_amdgcn_mfma_f32_16x16x32_bf16(pf, vf, o_acc[nt], 0, 0, 0);
            }
        }
    }

    __syncthreads();
    float* red = (float*)Ks;
    if (kh == 1) {
        f32x4* base = (f32x4*)&red[(qc * 64 + l) * 16];
        base[0] = o_acc[0]; base[1] = o_acc[1]; base[2] = o_acc[2];
        f32x4 lv; lv[0] = l_i[0]; lv[1] = l_i[1]; lv[2] = l_i[2]; lv[3] = l_i[3];
        base[3] = lv;
    }
    __syncthreads();
    if (kh == 0) {
        f32x4* base = (f32x4*)&red[(qc * 64 + l) * 16];
        o_acc[0] += base[0]; o_acc[1] += base[1]; o_acc[2] += base[2];
        f32x4 lv = base[3];
#pragma unroll
        for (int r = 0; r < 4; ++r) {
            float lsum = l_i[r] + lv[r];
#pragma unroll
            for (int o = 8; o; o >>= 1) lsum += __shfl_xor(lsum, o, 64);
            float inv = 1.f / lsum;
#pragma unroll
            for (int nt = 0; nt < 3; ++nt)
                outp[(size_t)(b * NTOK + q0 + qc * 16 + quad * 4 + r) * DIM
                     + h * 48 + nt * 16 + lm]
                    = __float2bfloat16(o_acc[nt][r] * inv);
        }
    }
}

// ---------------------------------------------------------------------------
extern "C" void kernel_launch(void* const* d_in, const int* in_sizes, int n_in,
                              void* d_out, int out_size, void* d_ws, size_t ws_size,
                              hipStream_t stream) {
    const float* x    = (const float*)d_in[0];
    const float* g1   = (const float*)d_in[1];
    const float* b1   = (const float*)d_in[2];
    const float* Wqkv = (const float*)d_in[3];
    const float* Wo   = (const float*)d_in[4];
    const float* bo   = (const float*)d_in[5];
    const float* g2   = (const float*)d_in[6];
    const float* b2   = (const float*)d_in[7];
    const float* W1   = (const float*)d_in[8];
    const float* b1m  = (const float*)d_in[9];
    const float* W2   = (const float*)d_in[10];
    const float* b2m  = (const float*)d_in[11];
    float* out = (float*)d_out;

    char* p = (char*)d_ws;
    float* bufH = (float*)p;                       p += (size_t)TOKS * DIM * 4;      // f32 [4096,384]
    char* qkvp = p;
    __hip_bfloat16* bufQKVb = (__hip_bfloat16*)p;  p += (size_t)TOKS * 3 * DIM * 2;  // bf16 [4096,1152]
    __hip_bfloat16* bufVT   = (__hip_bfloat16*)p;  p += (size_t)TOKS * DIM * 2;      // bf16 [16,48,2048]
    __hip_bfloat16* bufNb   = (__hip_bfloat16*)p;  p += (size_t)TOKS * DIM * 2;      // bf16 [4096,384]
    __hip_bfloat16* bufAb   = (__hip_bfloat16*)p;  p += (size_t)TOKS * DIM * 2;      // bf16 [4096,384]
    __hip_bfloat16* WqkvT   = (__hip_bfloat16*)p;  p += (size_t)3 * DIM * DIM * 2;   // [1152,384]
    __hip_bfloat16* WoT     = (__hip_bfloat16*)p;  p += (size_t)DIM * DIM * 2;       // [384,384]
    __hip_bfloat16* W1T     = (__hip_bfloat16*)p;  p += (size_t)HIDDEN * DIM * 2;    // [1536,384]
    __hip_bfloat16* W2T     = (__hip_bfloat16*)p;  p += (size_t)DIM * HIDDEN * 2;    // [384,1536]
    __hip_bfloat16* bufHIDb = (__hip_bfloat16*)qkvp;  // bf16 [4096,1536] overlays QKV+VT

    // 0. Wqkv transpose + input transpose/LN1 (critical path only)
    prep<<<432 + 128, 256, 0, stream>>>(Wqkv, WqkvT, x, g1, b1, bufH, bufNb);
    // 1. QKV projection (BK=64, swizzled) + Wo/W1/W2 transposes backfilled
    qkv_gemm_xpose<<<1152 + 1296, 256, 0, stream>>>(
        bufNb, WqkvT, bufQKVb, bufVT, Wo, W1, W2, WoT, W1T, W2T);
    // 2. MFMA flash attention -> bf16 (R6 champion structure)
    attn_mfma<<<dim3(NTOK / 64, NHEAD, BATCH), 512, 0, stream>>>(
        (const u16*)bufQKVb, (const u16*)bufVT, bufAb);
    // 3. fused output projection + bias + residual + LN2 (R6 champion)
    wo_ln<<<TOKS / 16, 256, 0, stream>>>(bufAb, WoT, bo, g2, b2, bufH, bufNb);
    // 4. MLP up + GELU -> bf16 hidden (BK=64, 8 blocks/CU)
    gemm_mfma<64, true><<<dim3(HIDDEN / 64, TOKS / 64), 256, 0, stream>>>(
        bufNb, W1T, b1m, bufHIDb, TOKS, HIDDEN, DIM);
    // 5. MLP down + bias + residual -> out (32x64 tiles, 768 blocks = 3/CU)
    w2_gemm<<<dim3(DIM / 64, TOKS / 32), 256, 0, stream>>>(
        bufHIDb, W2T, b2m, bufH, out);
}